// Round 5
// baseline (249.720 us; speedup 1.0000x reference)
//
#include <hip/hip_runtime.h>
#include <math.h>

#define D  32
#define BN 16384
#define PP 16

typedef __bf16 bf16x8 __attribute__((ext_vector_type(8)));
typedef float  floatx4 __attribute__((ext_vector_type(4)));

// Weights image layout (bytes), one per hop, built by prep_weights:
//   [0, 18432)       W_ih bf16, 128 rows, row-stride 72 elems (k=0..63 valid)
//   [18432, 28672)   W_hh bf16, 128 rows, row-stride 40 elems (k=0..31 valid)
//   [28672, 29184)   bias f32[128] = b_ih + b_hh
//   [29184, 33792)   agg_w f32, 32 rows, row-stride 36 (k=0..31 valid)
//   [33792, 33920)   agg_b f32[32]
#define WIH_OFF     0
#define WHH_OFF     18432
#define BIAS_OFF    28672
#define AGG_OFF     29184
#define AGGB_OFF    33792
#define IMG_BYTES   33920
// After frag hoist, the W_ih region [0,18432) is dead -> reuse for X/H tiles.
#define X_OFF       0                // X: 64 rows stride 144 B (9216 B)
#define H_OFF       9216             // H: 64 rows stride  80 B (5120 B)
#define S_OFF       14336            // s vectors: 4 waves x 128 B

__device__ __forceinline__ float sigf(float x) {
    float e = __builtin_amdgcn_exp2f(-x * 1.44269504088896341f);
    return __builtin_amdgcn_rcpf(1.0f + e);
}
__device__ __forceinline__ float tanh_fast(float x) {
    float e = __builtin_amdgcn_exp2f(x * 2.88539008177792681f);  // exp(2x)
    return 1.0f - 2.0f * __builtin_amdgcn_rcpf(e + 1.0f);
}
__device__ __forceinline__ float logsigf(float x) {
    float ax = fabsf(x);
    float l = log1pf(__expf(-ax));
    return (x >= 0.0f) ? -l : x - l;
}

__device__ __forceinline__ void stage16(const float* __restrict__ src, char* dst) {
    const float4* s = (const float4*)src;
    float4 a = s[0], b = s[1], c = s[2], d = s[3];
    bf16x8 lo = { (__bf16)a.x, (__bf16)a.y, (__bf16)a.z, (__bf16)a.w,
                  (__bf16)b.x, (__bf16)b.y, (__bf16)b.z, (__bf16)b.w };
    bf16x8 hi = { (__bf16)c.x, (__bf16)c.y, (__bf16)c.z, (__bf16)c.w,
                  (__bf16)d.x, (__bf16)d.y, (__bf16)d.z, (__bf16)d.w };
    *(bf16x8*)dst        = lo;
    *(bf16x8*)(dst + 16) = hi;
}

__global__ __launch_bounds__(256)
void prep_weights(const float* __restrict__ w_ih, const float* __restrict__ w_hh,
                  const float* __restrict__ b_ih, const float* __restrict__ b_hh,
                  const float* __restrict__ agg_w, const float* __restrict__ agg_b,
                  float* __restrict__ img_f)
{
    char* base = (char*)img_f;
    const int t0 = blockIdx.x * 256 + threadIdx.x;     // 2048 threads
    for (int idx = t0; idx < 8192; idx += 2048) {
        int n = idx >> 6, k = idx & 63;
        ((__bf16*)(base + WIH_OFF))[n * 72 + k] = (__bf16)w_ih[idx];
    }
    for (int idx = t0; idx < 4096; idx += 2048) {
        int n = idx >> 5, k = idx & 31;
        ((__bf16*)(base + WHH_OFF))[n * 40 + k] = (__bf16)w_hh[idx];
    }
    if (t0 < 128)
        ((float*)(base + BIAS_OFF))[t0] = b_ih[t0] + b_hh[t0];
    if (t0 < 1024) {
        int r = t0 >> 5, k = t0 & 31;
        ((float*)(base + AGG_OFF))[r * 36 + k] = agg_w[t0];
    }
    if (t0 < 32)
        ((float*)(base + AGGB_OFF))[t0] = agg_b[t0];
}

// Block = 256 thr = 4 waves. Wave w owns all 16 p's of batch fb = blockIdx*4+w.
// Weight B-fragments hoisted to VGPRs once; step loop touches LDS only for
// X staging (2 b128 writes), A-frags (2-3 b128 reads) and h round-trip
// (8 b16 writes) per lane per step. Epilogue fuses the agg matvec.
template<int L, int T>
__global__ __launch_bounds__(256, 2)
void hop_mfma(const float* __restrict__ user_table,
              const float* __restrict__ ent_table,
              const float* __restrict__ rel_table,
              const float* __restrict__ img,
              const int*   __restrict__ users,
              const int*   __restrict__ items,
              const int*   __restrict__ lp,        // (NE,P,L)
              const float* __restrict__ src_emb,   // null -> ent_table[items[b]]
              float* __restrict__ emb_out)         // (B,32)
{
    __shared__ __align__(16) char lds[IMG_BYTES];

    const int tid  = threadIdx.x;
    const int lane = tid & 63;
    const int wave = tid >> 6;

    // ---- load weight image into LDS (block-wide) ---------------------------
    {
        const float4* g = (const float4*)img;
        float4* l = (float4*)lds;
        #pragma unroll
        for (int i = 0; i < 9; ++i) {
            int idx = i * 256 + tid;                 // IMG_BYTES/16 = 2120
            if (idx < IMG_BYTES / 16) l[idx] = g[idx];
        }
    }
    __syncthreads();

    const int ak  = (lane >> 4) * 8;               // A/B k-offset
    const int bnl = lane & 15;                     // B col within tile

    // ---- hoist weight fragments to registers (loop-invariant) --------------
    bf16x8 wb0[8], wb1[8], wbh[8];
    float  biasv[8];
    {
        const char* Wih = lds + WIH_OFF;
        const char* Whh = lds + WHH_OFF;
        const float* bias = (const float*)(lds + BIAS_OFF);
        #pragma unroll
        for (int nt = 0; nt < 8; ++nt) {
            const int bn = nt * 16 + bnl;
            wb0[nt] = *(const bf16x8*)(Wih + bn * 144 + ak * 2);
            wb1[nt] = *(const bf16x8*)(Wih + bn * 144 + 64 + ak * 2);
            wbh[nt] = *(const bf16x8*)(Whh + bn * 80 + ak * 2);
            biasv[nt] = bias[nt * 16 + bnl];
        }
    }
    __syncthreads();    // all waves done reading W_ih region before X clobbers

    char* Xl = lds + X_OFF;
    char* Hl = lds + H_OFF;

    // ---- staging role: thread stages 16 feats of row srow (wave-private) ---
    const int srow  = tid >> 2;          // wave w -> rows 16w..16w+15
    const int squad = tid & 3;
    const int spair = blockIdx.x * 64 + srow;
    const int sb    = spair >> 4;
    const int* __restrict__ sil = lp + ((size_t)items[sb] * PP + (spair & 15)) * L;
    const int suser = users[sb];
    char* sdst = Xl + srow * 144 + squad * 32;

    // ---- MFMA role ---------------------------------------------------------
    const int wrow = wave * 16;
    const int am   = wrow + (lane & 15);           // A row (pair)

    float cst[8]  = {0,0,0,0,0,0,0,0};
    float hout[8];
    floatx4 acc[8];
    #pragma unroll
    for (int nt = 0; nt < 8; ++nt) {
        floatx4 v = { biasv[nt], biasv[nt], biasv[nt], biasv[nt] };
        acc[nt] = v;
    }

    #pragma unroll
    for (int t = 0; t < T; ++t) {
        // stage X_t (wave-private rows)
        {
            const float* src;
            if (t == 0) {
                src = (squad < 2) ? user_table + (size_t)suser * D + squad * 16
                                  : ent_table + (size_t)sil[0] * D + (squad - 2) * 16;
            } else {
                src = (squad < 2) ? rel_table + (size_t)sil[2 * t - 1] * D + squad * 16
                                  : ent_table + (size_t)sil[2 * t]     * D + (squad - 2) * 16;
            }
            stage16(src, sdst);
        }

        bf16x8 ax0 = *(const bf16x8*)(Xl + am * 144 + ak * 2);
        bf16x8 ax1 = *(const bf16x8*)(Xl + am * 144 + 64 + ak * 2);
        bf16x8 ah  = {};
        if (t > 0) ah = *(const bf16x8*)(Hl + am * 80 + ak * 2);

        #pragma unroll
        for (int nt = 0; nt < 8; ++nt) {
            floatx4 a = acc[nt];
            a = __builtin_amdgcn_mfma_f32_16x16x32_bf16(ax0, wb0[nt], a, 0, 0, 0);
            a = __builtin_amdgcn_mfma_f32_16x16x32_bf16(ax1, wb1[nt], a, 0, 0, 0);
            if (t > 0)
                a = __builtin_amdgcn_mfma_f32_16x16x32_bf16(ah, wbh[nt], a, 0, 0, 0);
            acc[nt] = a;
        }

        // nonlinearities in C-layout: col=lane&15 (+16*nt), row=(lane>>4)*4+r
        #pragma unroll
        for (int ng = 0; ng < 2; ++ng) {
            floatx4 gi = acc[ng], gf = acc[ng + 2], gg = acc[ng + 4], go = acc[ng + 6];
            #pragma unroll
            for (int r = 0; r < 4; ++r) {
                float c = cst[ng * 4 + r];
                c = sigf(gf[r]) * c + sigf(gi[r]) * tanh_fast(gg[r]);
                cst[ng * 4 + r] = c;
                float h = sigf(go[r]) * tanh_fast(c);
                hout[ng * 4 + r] = h;
                if (t < T - 1) {
                    int pr = wrow + (lane >> 4) * 4 + r;
                    *(__bf16*)(Hl + pr * 80 + (ng * 16 + bnl) * 2) = (__bf16)h;
                }
            }
        }

        if (t < T - 1) {
            #pragma unroll
            for (int nt = 0; nt < 8; ++nt) {
                floatx4 v = { biasv[nt], biasv[nt], biasv[nt], biasv[nt] };
                acc[nt] = v;
            }
        }
    }

    // ---- epilogue: sum over p, add src emb, apply agg matvec ---------------
    const int fb = blockIdx.x * 4 + wave;
    float* s_l = (float*)(lds + S_OFF + wave * 128);   // wave-private 32 floats
    #pragma unroll
    for (int ng = 0; ng < 2; ++ng) {
        float v = hout[ng * 4 + 0] + hout[ng * 4 + 1] + hout[ng * 4 + 2] + hout[ng * 4 + 3];
        v += __shfl_xor(v, 16);
        v += __shfl_xor(v, 32);
        if (lane < 16) {
            const int k = ng * 16 + lane;
            float s = src_emb ? src_emb[(size_t)fb * D + k]
                              : ent_table[(size_t)items[fb] * D + k];
            s_l[k] = s + v;
        }
    }
    __syncthreads();   // (wave-private region; barrier is belt-and-braces)
    if (lane < 32) {
        const float* aw = (const float*)(lds + AGG_OFF) + lane * 36;
        float acc_o = ((const float*)(lds + AGGB_OFF))[lane];
        #pragma unroll
        for (int k = 0; k < D; ++k) acc_o = fmaf(s_l[k], aw[k], acc_o);
        emb_out[(size_t)fb * D + lane] = acc_o;
    }
}

__global__ __launch_bounds__(256)
void score_kernel(const float* __restrict__ user_table,
                  const float* __restrict__ emb,
                  const int*   __restrict__ users,
                  const int*   __restrict__ items,
                  const int*   __restrict__ ratings,
                  float* __restrict__ out,
                  float* __restrict__ partials)
{
    __shared__ float red[4];
    const int t = threadIdx.x;
    const int b = blockIdx.x * 256 + t;
    const float* __restrict__ u = user_table + (size_t)users[b] * D;
    const float* __restrict__ e = emb + (size_t)b * D;
    float s = 0.0f;
    #pragma unroll
    for (int k = 0; k < D; ++k) s = fmaf(u[k], e[k], s);
    out[1 + b]      = sigf(s);
    out[1 + BN + b] = (float)items[b];
    float r = (float)ratings[b];
    float term = r * logsigf(s) + (1.0f - r) * logsigf(-s);
    #pragma unroll
    for (int m = 1; m < 64; m <<= 1) term += __shfl_xor(term, m);
    if ((t & 63) == 0) red[t >> 6] = term;
    __syncthreads();
    if (t == 0) partials[blockIdx.x] = red[0] + red[1] + red[2] + red[3];
}

__global__ void loss_kernel(const float* __restrict__ partials, float* __restrict__ out)
{
    const int t = threadIdx.x;   // 64 threads
    float v = partials[t];
    #pragma unroll
    for (int m = 1; m < 64; m <<= 1) v += __shfl_xor(v, m);
    if (t == 0) out[0] = -v / (float)BN;
}

extern "C" void kernel_launch(void* const* d_in, const int* in_sizes, int n_in,
                              void* d_out, int out_size, void* d_ws, size_t ws_size,
                              hipStream_t stream)
{
    const float* user_table = (const float*)d_in[0];
    const float* ent_table  = (const float*)d_in[1];
    const float* rel_table  = (const float*)d_in[2];
    const float* w_ih0 = (const float*)d_in[3];
    const float* w_hh0 = (const float*)d_in[4];
    const float* b_ih0 = (const float*)d_in[5];
    const float* b_hh0 = (const float*)d_in[6];
    const float* w_ih1 = (const float*)d_in[7];
    const float* w_hh1 = (const float*)d_in[8];
    const float* b_ih1 = (const float*)d_in[9];
    const float* b_hh1 = (const float*)d_in[10];
    const float* agg_w = (const float*)d_in[11];
    const float* agg_b = (const float*)d_in[12];
    const int* users   = (const int*)d_in[13];
    const int* items   = (const int*)d_in[14];
    const int* ratings = (const int*)d_in[15];
    const int* lp0     = (const int*)d_in[16];
    const int* lp1     = (const int*)d_in[17];
    float* out = (float*)d_out;

    float* ws       = (float*)d_ws;
    float* emb0     = ws;                            // B*32
    float* emb1     = ws + (size_t)BN * D;           // B*32
    float* partials = ws + 2 * (size_t)BN * D;       // 64
    float* img0     = ws + 2 * (size_t)BN * D + 64;  // IMG_BYTES
    float* img1     = img0 + IMG_BYTES / 4;

    prep_weights<<<8, 256, 0, stream>>>(w_ih0, w_hh0, b_ih0, b_hh0, agg_w, agg_b, img0);
    prep_weights<<<8, 256, 0, stream>>>(w_ih1, w_hh1, b_ih1, b_hh1, agg_w, agg_b, img1);

    const int hop_blocks = (BN * PP) / 64;           // 4096
    hop_mfma<3, 2><<<hop_blocks, 256, 0, stream>>>(
        user_table, ent_table, rel_table, img0, users, items, lp0, nullptr, emb0);
    hop_mfma<5, 3><<<hop_blocks, 256, 0, stream>>>(
        user_table, ent_table, rel_table, img1, users, items, lp1, emb0, emb1);
    score_kernel<<<BN / 256, 256, 0, stream>>>(
        user_table, emb1, users, items, ratings, out, partials);
    loss_kernel<<<1, 64, 0, stream>>>(partials, out);
}